// Round 3
// baseline (756.565 us; speedup 1.0000x reference)
//
#include <hip/hip_runtime.h>
#include <hip/hip_fp16.h>
#include <math.h>

// DeeperGCN on MI355X. N=50000, E=625000, D=128, L=7.
// fp16 inter-kernel streams; gather tables (h16, comb16) PRE-SCALED by
// log2(e) so the aggregation logit is a direct packed-fp16 add/max chain;
// CSR-by-dst build; FUSED per-layer kernel: 4 waves x 16 nodes/block --
// wave-sequential aggregation (64-lane rows, packed u32 records preloaded
// 64-wide + v_readlane extraction, 16-edge burst gather pipeline) into a
// padded LDS t-tile, then MFMA GEMM (transposed product) with fused
// bias/res/LN(+ReLU). h16 ping-pong (hA/hB) removes the cross-block
// write-while-gather race. No t16 round-trip, no degree sort.

constexpr int D = 128;
constexpr int NA = 9;   // atom feats
constexpr int NB = 3;   // bond feats
constexpr float L2E = 1.4426950408889634f;   // log2(e)
constexpr float INV_L2E = 0.6931471805599453f;

using half8  = __attribute__((ext_vector_type(8))) _Float16;
using h2v    = __attribute__((ext_vector_type(2))) _Float16;
using floatx4 = __attribute__((ext_vector_type(4))) float;

// ------------------------- CSR build -------------------------

__global__ void k_hist(const int* __restrict__ dst, int* __restrict__ deg, int E) {
    int e = blockIdx.x * 256 + threadIdx.x;
    if (e < E) atomicAdd(&deg[dst[e]], 1);
}

__global__ void k_scan_a(const int* __restrict__ deg, int* __restrict__ offs,
                         int* __restrict__ bsum, int N) {
    __shared__ int s[256];
    int i = blockIdx.x * 256 + threadIdx.x;
    int v = (i < N) ? deg[i] : 0;
    s[threadIdx.x] = v;
    __syncthreads();
    for (int d = 1; d < 256; d <<= 1) {
        int add = (threadIdx.x >= d) ? s[threadIdx.x - d] : 0;
        __syncthreads();
        s[threadIdx.x] += add;
        __syncthreads();
    }
    if (i < N) offs[i + 1] = s[threadIdx.x];
    if (threadIdx.x == 255) bsum[blockIdx.x] = s[255];
    if (i == 0) offs[0] = 0;
}

// nb must be <= 256 (N=50000 -> nb=196)
__global__ void k_scan_b(const int* __restrict__ bsum, int* __restrict__ bexc, int nb) {
    __shared__ int s[256];
    int t = threadIdx.x;
    int v = (t < nb) ? bsum[t] : 0;
    s[t] = v;
    __syncthreads();
    for (int d = 1; d < 256; d <<= 1) {
        int add = (t >= d) ? s[t - d] : 0;
        __syncthreads();
        s[t] += add;
        __syncthreads();
    }
    if (t < nb) bexc[t] = s[t] - v;  // exclusive block prefix
}

__global__ void k_scan_c(int* __restrict__ offs, const int* __restrict__ bexc, int N) {
    int i = blockIdx.x * 256 + threadIdx.x;
    if (i < N) offs[i + 1] += bexc[blockIdx.x];
}

// packed record: src (17 bits, N<2^17) | cidx<<17 (9 bits)
__global__ void k_fill(const int* __restrict__ src, const int* __restrict__ dst,
                       const int* __restrict__ attr, const int* __restrict__ offs,
                       int* __restrict__ cur, unsigned* __restrict__ recs1, int E) {
    int e = blockIdx.x * 256 + threadIdx.x;
    if (e >= E) return;
    int d = dst[e];
    int pos = offs[d] + atomicAdd(&cur[d], 1);
    unsigned cidx = (unsigned)(attr[e * 3] * 64 + attr[e * 3 + 1] * 8 + attr[e * 3 + 2]);
    recs1[pos] = (unsigned)src[e] | (cidx << 17);
}

// comb16[c][d] = fp16(L2E * (b0[c>>6][d] + b1[(c>>3)&7][d] + b2[c&7][d]))
__global__ void k_comb(const float* __restrict__ bemb, __half* __restrict__ comb16) {
    int gid = blockIdx.x * 256 + threadIdx.x;  // 512*32 float4s
    int c = gid >> 5, q = gid & 31;
    int a0 = c >> 6, a1 = (c >> 3) & 7, a2 = c & 7;
    float4 v0 = *(const float4*)(bemb + (a0)*D + q * 4);
    float4 v1 = *(const float4*)(bemb + (8 + a1) * D + q * 4);
    float4 v2 = *(const float4*)(bemb + (16 + a2) * D + q * 4);
    __half2* c2 = (__half2*)comb16;
    c2[c * 64 + q * 2]     = __floats2half2_rn(L2E * (v0.x + v1.x + v2.x),
                                               L2E * (v0.y + v1.y + v2.y));
    c2[c * 64 + q * 2 + 1] = __floats2half2_rn(L2E * (v0.z + v1.z + v2.z),
                                               L2E * (v0.w + v1.w + v2.w));
}

// Wt16[l][f][k] = fp16(W[l][k][f])  -- K-major transposed fp16 weights
__global__ void k_wt(const float* __restrict__ W, __half* __restrict__ Wt16, int total) {
    int o = blockIdx.x * 256 + threadIdx.x;
    if (o >= total) return;
    int l = o >> 14;          // /(128*128)
    int rem = o & 16383;
    int f = rem >> 7, k = rem & 127;
    Wt16[o] = __float2half_rn(W[(l << 14) + k * 128 + f]);
}

// ------------------------- Atom encoder (scaled h16) -------------------------

__global__ void k_atom(const int* __restrict__ x, const float* __restrict__ aemb,
                       __half* __restrict__ h16, int N) {
    int wid = (blockIdx.x * blockDim.x + threadIdx.x) >> 6;
    int lane = threadIdx.x & 63;
    if (wid >= N) return;
    const int* xr = x + wid * NA;
    float ax = 0.f, ay = 0.f;
#pragma unroll
    for (int f = 0; f < NA; ++f) {
        int v = xr[f];  // wave-uniform broadcast
        const float2 e = *(const float2*)(aemb + (f * 64 + v) * D + 2 * lane);
        ax += e.x; ay += e.y;
    }
    ((__half2*)h16)[wid * 64 + lane] = __floats2half2_rn(ax * L2E, ay * L2E);
}

// ------------------------- Fused layer: agg + GEMM + LN ---------------------
// Phase 1 (agg): wave w aggregates nodes [blk*64+w*16, +16) sequentially.
// Tables pre-scaled by L2E: u = max(h'+c', 0); p = exp2(u); S += p, W += p*u;
// t = (h' + W/S)/L2E written to LDS tile tt[64][136] (pad 8 halves -> 2-way
// max bank aliasing, free). Records preloaded 64-wide, v_readlane extract,
// scalar-addressed row gathers, 16-edge burst pipeline.
// Phase 2 (gemm): D[f][node] = sum_k Wt16[f][k]*tt[node][k] via
// v_mfma_f32_16x16x32_f16; C/D col(lane&15)=node, row(quad*4+reg)=f.
// LN = per-lane sums + shfl_xor(16,32).
// MODE 0: hres16 = o (fp16); hout = fp16(L2E*relu(LN(o))).
// MODE 1: out = LN(o) fp32.

template <int MODE>
__global__ __launch_bounds__(256) void k_fused(
    const __half* __restrict__ hin,
    const unsigned* __restrict__ recs1,
    const int* __restrict__ offs,
    const __half* __restrict__ comb16,
    const __half* __restrict__ Wt16,
    const float* __restrict__ bl,
    __half* __restrict__ hres16,
    const float* __restrict__ g,
    const float* __restrict__ bta,
    __half* __restrict__ hout,
    float* __restrict__ out,
    int N, int useRes) {
    __shared__ __align__(16) __half tt[64 * 136];
    int lane = threadIdx.x & 63;
    int wave = threadIdx.x >> 6;
    int nbase = blockIdx.x * 64 + wave * 16;

    // this wave's 17 CSR offsets in one coalesced load
    int oidx = nbase + lane;
    oidx = (oidx <= N) ? oidx : N;
    int offv = (lane < 17) ? offs[oidx] : 0;

    const h2v* hrow = (const h2v*)hin + lane;    // row r at hrow[r*64]
    const h2v* crow = (const h2v*)comb16 + lane;
    const h2v zero2 = (h2v)(_Float16)0;

#pragma unroll 1
    for (int j = 0; j < 16; ++j) {
        int nid = nbase + j;
        int nc = (nid < N) ? nid : N - 1;
        int su = __builtin_amdgcn_readlane(offv, j);
        int eu = __builtin_amdgcn_readlane(offv, j + 1);
        h2v hm2 = hrow[nc * 64];  // scaled self row
        float hsx = (float)hm2[0], hsy = (float)hm2[1];
        float tx, ty;
        if (su >= eu) {  // empty segment: m = 0; descale
            tx = hsx * INV_L2E;
            ty = hsy * INV_L2E;
        } else {
            float Sx = 0.f, Sy = 0.f, Wx = 0.f, Wy = 0.f;
            h2v hq[16], cq[16];
            int e0 = su;
            do {
                int lastc = (eu < e0 + 64) ? eu : e0 + 64;  // chunk end
                int last = lastc - 1;
                int ridx = e0 + lane;
                ridx = (ridx < eu - 1) ? ridx : eu - 1;
                unsigned recv = recs1[ridx];  // chunk records, one load

                auto load4 = [&](int base, int slot) {
#pragma unroll
                    for (int i = 0; i < 4; ++i) {
                        int idx = base + i; idx = (idx < last) ? idx : last;
                        unsigned r = __builtin_amdgcn_readlane(recv, idx - e0);
                        int sj = (int)(r & 0x1FFFFu);
                        int cj = (int)(r >> 17);
                        hq[slot * 4 + i] = hrow[sj * 64];  // saddr + lane*4
                        cq[slot * 4 + i] = crow[cj * 64];
                    }
                };
                auto comp4u = [&](int slot) {
#pragma unroll
                    for (int i = 0; i < 4; ++i) {
                        h2v m = hq[slot * 4 + i] + cq[slot * 4 + i];
                        m = __builtin_elementwise_max(m, zero2);
                        float u0 = (float)m[0], u1 = (float)m[1];
                        float px = __builtin_amdgcn_exp2f(u0);
                        float py = __builtin_amdgcn_exp2f(u1);
                        Sx += px; Sy += py;
                        Wx = fmaf(px, u0, Wx);
                        Wy = fmaf(py, u1, Wy);
                    }
                };
                auto comp4m = [&](int gb, int slot) {
#pragma unroll
                    for (int i = 0; i < 4; ++i) {
                        h2v m = hq[slot * 4 + i] + cq[slot * 4 + i];
                        m = __builtin_elementwise_max(m, zero2);
                        float u0 = (float)m[0], u1 = (float)m[1];
                        bool valid = (gb + i) < lastc;  // wave-uniform
                        float px = valid ? __builtin_amdgcn_exp2f(u0) : 0.f;
                        float py = valid ? __builtin_amdgcn_exp2f(u1) : 0.f;
                        Sx += px; Sy += py;
                        Wx = fmaf(px, u0, Wx);
                        Wy = fmaf(py, u1, Wy);
                    }
                };

                load4(e0, 0);
                if (e0 + 4  < lastc) load4(e0 + 4, 1);
                if (e0 + 8  < lastc) load4(e0 + 8, 2);
                if (e0 + 12 < lastc) load4(e0 + 12, 3);

                int e = e0;
                for (; e + 16 < lastc; e += 16) {  // steady: 16 live edges
                    comp4u(0); comp4u(1); comp4u(2); comp4u(3);
                    load4(e + 16, 0); load4(e + 20, 1);
                    load4(e + 24, 2); load4(e + 28, 3);
                }
                comp4m(e, 0);
                if (e + 4  < lastc) comp4m(e + 4, 1);
                if (e + 8  < lastc) comp4m(e + 8, 2);
                if (e + 12 < lastc) comp4m(e + 12, 3);

                e0 = lastc;
            } while (e0 < eu);
            tx = (hsx + Wx / (Sx + 1e-16f)) * INV_L2E;
            ty = (hsy + Wy / (Sy + 1e-16f)) * INV_L2E;
        }
        ((__half2*)tt)[(wave * 16 + j) * 68 + lane] = __floats2half2_rn(tx, ty);
    }
    __syncthreads();

    // ---------------- GEMM + LN phase ----------------
    int quad = lane >> 4, col = lane & 15;
    int node = blockIdx.x * 64 + wave * 16 + col;
    bool nok = node < N;
    int nc2 = nok ? node : N - 1;

    const __half* trow = tt + (size_t)(wave * 16 + col) * 136;
    half8 bfrag[4];
#pragma unroll
    for (int ks = 0; ks < 4; ++ks)
        bfrag[ks] = *(const half8*)(trow + ks * 32 + quad * 8);

    floatx4 acc[8];
#pragma unroll
    for (int ft = 0; ft < 8; ++ft) acc[ft] = (floatx4){0.f, 0.f, 0.f, 0.f};

#pragma unroll
    for (int ft = 0; ft < 8; ++ft) {
        const __half* wrow = Wt16 + (size_t)(ft * 16 + col) * 128;  // A-op: m=f
#pragma unroll
        for (int ks = 0; ks < 4; ++ks) {
            half8 afrag = *(const half8*)(wrow + ks * 32 + quad * 8);
            acc[ft] = __builtin_amdgcn_mfma_f32_16x16x32_f16(afrag, bfrag[ks],
                                                             acc[ft], 0, 0, 0);
        }
    }

    float s = 0.f, ss = 0.f;
#pragma unroll
    for (int ft = 0; ft < 8; ++ft) {
        int f0 = ft * 16 + quad * 4;  // 4 consecutive features per lane
        float4 bb = *(const float4*)(bl + f0);
        float o0 = acc[ft][0] + bb.x, o1 = acc[ft][1] + bb.y;
        float o2 = acc[ft][2] + bb.z, o3 = acc[ft][3] + bb.w;
        if (useRes) {
            uint2 rr = *(const uint2*)(hres16 + (size_t)nc2 * 128 + f0);
            __half2 r01 = *(__half2*)&rr.x, r23 = *(__half2*)&rr.y;
            o0 += __low2float(r01); o1 += __high2float(r01);
            o2 += __low2float(r23); o3 += __high2float(r23);
        }
        acc[ft][0] = o0; acc[ft][1] = o1; acc[ft][2] = o2; acc[ft][3] = o3;
        s += (o0 + o1) + (o2 + o3);
        ss += fmaf(o0, o0, o1 * o1) + fmaf(o2, o2, o3 * o3);
        if (MODE == 0 && nok) {
            __half2 h01 = __floats2half2_rn(o0, o1);
            __half2 h23 = __floats2half2_rn(o2, o3);
            uint2 pk = make_uint2(*(unsigned*)&h01, *(unsigned*)&h23);
            *(uint2*)(hres16 + (size_t)node * 128 + f0) = pk;
        }
    }
    s += __shfl_xor(s, 16, 64);  ss += __shfl_xor(ss, 16, 64);
    s += __shfl_xor(s, 32, 64);  ss += __shfl_xor(ss, 32, 64);
    float mu = s * (1.f / 128.f);
    float var = ss * (1.f / 128.f) - mu * mu;
    float rs = rsqrtf(var + 1e-5f);

#pragma unroll
    for (int ft = 0; ft < 8; ++ft) {
        int f0 = ft * 16 + quad * 4;
        float4 gg = *(const float4*)(g + f0);
        float4 bt = *(const float4*)(bta + f0);
        float l0 = (acc[ft][0] - mu) * rs * gg.x + bt.x;
        float l1 = (acc[ft][1] - mu) * rs * gg.y + bt.y;
        float l2 = (acc[ft][2] - mu) * rs * gg.z + bt.z;
        float l3 = (acc[ft][3] - mu) * rs * gg.w + bt.w;
        if (MODE == 0) {
            l0 = fmaxf(l0, 0.f); l1 = fmaxf(l1, 0.f);
            l2 = fmaxf(l2, 0.f); l3 = fmaxf(l3, 0.f);
            if (nok) {
                __half2 h01 = __floats2half2_rn(l0 * L2E, l1 * L2E);
                __half2 h23 = __floats2half2_rn(l2 * L2E, l3 * L2E);
                uint2 pk = make_uint2(*(unsigned*)&h01, *(unsigned*)&h23);
                *(uint2*)(hout + (size_t)node * 128 + f0) = pk;
            }
        } else {
            if (nok)
                *(float4*)(out + (size_t)node * 128 + f0) =
                    make_float4(l0, l1, l2, l3);
        }
    }
}

// ------------------------- Launch -------------------------

extern "C" void kernel_launch(void* const* d_in, const int* in_sizes, int n_in,
                              void* d_out, int out_size, void* d_ws, size_t ws_size,
                              hipStream_t stream) {
    const int*   x    = (const int*)d_in[0];
    const int*   ei   = (const int*)d_in[1];
    const int*   attr = (const int*)d_in[2];
    const float* aemb = (const float*)d_in[3];
    const float* bemb = (const float*)d_in[4];
    const float* Wf   = (const float*)d_in[5];
    const float* bf   = (const float*)d_in[6];
    const float* gam  = (const float*)d_in[7];
    const float* bet  = (const float*)d_in[8];
    float* out = (float*)d_out;

    const int N = in_sizes[0] / NA;        // 50000
    const int E = in_sizes[1] / 2;         // 625000
    const int L = in_sizes[5] / (D * D);   // 7

    char* ws = (char*)d_ws;
    size_t o = 0;
    auto carve = [&](size_t bytes) -> void* {
        void* p = (void*)(ws + o);
        o += (bytes + 255) & ~(size_t)255;
        return p;
    };
    __half* hres16 = (__half*)carve((size_t)N * D * 2);  // fp16 residual chain
    __half* hA     = (__half*)carve((size_t)N * D * 2);  // gather table ping
    __half* hB     = (__half*)carve((size_t)N * D * 2);  // gather table pong
    unsigned* recs1 = (unsigned*)carve((size_t)E * 4);   // packed records
    __half* comb16 = (__half*)carve(512 * D * 2);
    __half* Wt16   = (__half*)carve((size_t)L * D * D * 2);
    int*    deg    = (int*)carve((size_t)N * 4);
    int*    cur    = (int*)carve((size_t)N * 4);
    int*    offs   = (int*)carve((size_t)(N + 1) * 4);
    int*    bsum   = (int*)carve(4096);
    int*    bexc   = (int*)carve(4096);

    const int* src = ei;
    const int* dst = ei + E;

    hipMemsetAsync(deg, 0, (size_t)N * 4, stream);
    hipMemsetAsync(cur, 0, (size_t)N * 4, stream);

    int ebl = (E + 255) / 256;
    int nbl = (N + 255) / 256;  // 196 (<=256 required by k_scan_b)
    k_comb<<<64, 256, 0, stream>>>(bemb, comb16);
    int wtot = L * D * D;
    k_wt<<<(wtot + 255) / 256, 256, 0, stream>>>(Wf, Wt16, wtot);
    k_hist<<<ebl, 256, 0, stream>>>(dst, deg, E);
    k_scan_a<<<nbl, 256, 0, stream>>>(deg, offs, bsum, N);
    k_scan_b<<<1, 256, 0, stream>>>(bsum, bexc, nbl);
    k_scan_c<<<nbl, 256, 0, stream>>>(offs, bexc, N);
    k_fill<<<ebl, 256, 0, stream>>>(src, dst, attr, offs, cur, recs1, E);

    int wbl = (N * 64 + 255) / 256;  // wave per node
    k_atom<<<wbl, 256, 0, stream>>>(x, aemb, hA, N);

    int gbl = (N + 63) / 64;  // 782 blocks, 64 nodes each
    for (int l = 0; l < L; ++l) {
        const __half* hi = (l & 1) ? hB : hA;
        __half* ho = (l & 1) ? hA : hB;
        if (l == L - 1) {
            k_fused<1><<<gbl, 256, 0, stream>>>(hi, recs1, offs, comb16,
                                                Wt16 + l * D * D, bf + l * D,
                                                hres16, gam + l * D, bet + l * D,
                                                ho, out, N, 1);
        } else {
            k_fused<0><<<gbl, 256, 0, stream>>>(hi, recs1, offs, comb16,
                                                Wt16 + l * D * D, bf + l * D,
                                                hres16, gam + l * D, bet + l * D,
                                                ho, out, N, l > 0 ? 1 : 0);
        }
    }
}

// Round 4
// 666.037 us; speedup vs baseline: 1.1359x; 1.1359x over previous
//
#include <hip/hip_runtime.h>
#include <hip/hip_fp16.h>
#include <math.h>

// DeeperGCN on MI355X. N=50000, E=625000, D=128, L=7.
// fp16 inter-kernel streams; gather tables (h16, comb16) PRE-SCALED by
// log2(e) so the aggregation logit is a direct packed-fp16 add/max chain;
// CSR-by-dst build; EDGE-BALANCED wave partition (each wave owns the
// consecutive nodes whose CSR segments start in a 32-edge bucket -> ~32
// edges/wave, preamble amortized, no sort, no perm); k_agg: 64-lane rows,
// packed u32 records preloaded 64-wide + v_readlane extraction, 16-edge
// burst gather pipeline; MFMA GEMM (transposed product, zero LDS) with
// fused bias/res/LN(+ReLU).

constexpr int D = 128;
constexpr int NA = 9;   // atom feats
constexpr int NB = 3;   // bond feats
constexpr int CEDGE = 32;  // target edges per wave
constexpr float L2E = 1.4426950408889634f;   // log2(e)
constexpr float INV_L2E = 0.6931471805599453f;

using half8  = __attribute__((ext_vector_type(8))) _Float16;
using h2v    = __attribute__((ext_vector_type(2))) _Float16;
using floatx4 = __attribute__((ext_vector_type(4))) float;

// ------------------------- CSR build -------------------------

__global__ void k_hist(const int* __restrict__ dst, int* __restrict__ deg, int E) {
    int e = blockIdx.x * 256 + threadIdx.x;
    if (e < E) atomicAdd(&deg[dst[e]], 1);
}

__global__ void k_scan_a(const int* __restrict__ deg, int* __restrict__ offs,
                         int* __restrict__ bsum, int N) {
    __shared__ int s[256];
    int i = blockIdx.x * 256 + threadIdx.x;
    int v = (i < N) ? deg[i] : 0;
    s[threadIdx.x] = v;
    __syncthreads();
    for (int d = 1; d < 256; d <<= 1) {
        int add = (threadIdx.x >= d) ? s[threadIdx.x - d] : 0;
        __syncthreads();
        s[threadIdx.x] += add;
        __syncthreads();
    }
    if (i < N) offs[i + 1] = s[threadIdx.x];
    if (threadIdx.x == 255) bsum[blockIdx.x] = s[255];
    if (i == 0) offs[0] = 0;
}

// nb must be <= 256 (N=50000 -> nb=196)
__global__ void k_scan_b(const int* __restrict__ bsum, int* __restrict__ bexc, int nb) {
    __shared__ int s[256];
    int t = threadIdx.x;
    int v = (t < nb) ? bsum[t] : 0;
    s[t] = v;
    __syncthreads();
    for (int d = 1; d < 256; d <<= 1) {
        int add = (t >= d) ? s[t - d] : 0;
        __syncthreads();
        s[t] += add;
        __syncthreads();
    }
    if (t < nb) bexc[t] = s[t] - v;  // exclusive block prefix
}

__global__ void k_scan_c(int* __restrict__ offs, const int* __restrict__ bexc, int N) {
    int i = blockIdx.x * 256 + threadIdx.x;
    if (i < N) offs[i + 1] += bexc[blockIdx.x];
}

// packed record: src (17 bits, N<2^17) | cidx<<17 (9 bits)
__global__ void k_fill(const int* __restrict__ src, const int* __restrict__ dst,
                       const int* __restrict__ attr, const int* __restrict__ offs,
                       int* __restrict__ cur, unsigned* __restrict__ recs1, int E) {
    int e = blockIdx.x * 256 + threadIdx.x;
    if (e >= E) return;
    int d = dst[e];
    int pos = offs[d] + atomicAdd(&cur[d], 1);
    unsigned cidx = (unsigned)(attr[e * 3] * 64 + attr[e * 3 + 1] * 8 + attr[e * 3 + 2]);
    recs1[pos] = (unsigned)src[e] | (cidx << 17);
}

// ---------------- edge-balanced wave partition ----------------
// Node n belongs to wave offs[n]/CEDGE. wstart[w] = first node of wave w;
// wstart[NW] = N. Boundaries are disjoint across threads (offs monotone).
__global__ void k_part(const int* __restrict__ offs, int* __restrict__ wstart,
                       int N, int NW) {
    int n = blockIdx.x * 256 + threadIdx.x;
    if (n >= N) return;
    int a = offs[n] / CEDGE;
    int b = offs[n + 1] / CEDGE;
    if (n == 0) wstart[0] = 0;
    for (int w = a + 1; w <= b; ++w) wstart[w] = n + 1;
    if (n == N - 1)
        for (int w = b + 1; w <= NW; ++w) wstart[w] = N;
}

// comb16[c][d] = fp16(L2E * (b0[c>>6][d] + b1[(c>>3)&7][d] + b2[c&7][d]))
__global__ void k_comb(const float* __restrict__ bemb, __half* __restrict__ comb16) {
    int gid = blockIdx.x * 256 + threadIdx.x;  // 512*32 float4s
    int c = gid >> 5, q = gid & 31;
    int a0 = c >> 6, a1 = (c >> 3) & 7, a2 = c & 7;
    float4 v0 = *(const float4*)(bemb + (a0)*D + q * 4);
    float4 v1 = *(const float4*)(bemb + (8 + a1) * D + q * 4);
    float4 v2 = *(const float4*)(bemb + (16 + a2) * D + q * 4);
    __half2* c2 = (__half2*)comb16;
    c2[c * 64 + q * 2]     = __floats2half2_rn(L2E * (v0.x + v1.x + v2.x),
                                               L2E * (v0.y + v1.y + v2.y));
    c2[c * 64 + q * 2 + 1] = __floats2half2_rn(L2E * (v0.z + v1.z + v2.z),
                                               L2E * (v0.w + v1.w + v2.w));
}

// Wt16[l][f][k] = fp16(W[l][k][f])  -- K-major transposed fp16 weights
__global__ void k_wt(const float* __restrict__ W, __half* __restrict__ Wt16, int total) {
    int o = blockIdx.x * 256 + threadIdx.x;
    if (o >= total) return;
    int l = o >> 14;          // /(128*128)
    int rem = o & 16383;
    int f = rem >> 7, k = rem & 127;
    Wt16[o] = __float2half_rn(W[(l << 14) + k * 128 + f]);
}

// ------------------------- Atom encoder (scaled h16) -------------------------

__global__ void k_atom(const int* __restrict__ x, const float* __restrict__ aemb,
                       __half* __restrict__ h16, int N) {
    int wid = (blockIdx.x * blockDim.x + threadIdx.x) >> 6;
    int lane = threadIdx.x & 63;
    if (wid >= N) return;
    const int* xr = x + wid * NA;
    float ax = 0.f, ay = 0.f;
#pragma unroll
    for (int f = 0; f < NA; ++f) {
        int v = xr[f];  // wave-uniform broadcast
        const float2 e = *(const float2*)(aemb + (f * 64 + v) * D + 2 * lane);
        ax += e.x; ay += e.y;
    }
    ((__half2*)h16)[wid * 64 + lane] = __floats2half2_rn(ax * L2E, ay * L2E);
}

// ------------------------- Aggregation ------------------------------------
// wave w processes nodes [wstart[w], wstart[w+1]) -- ~CEDGE edges total.
// Tables pre-scaled by L2E: logit u = max(h'+c',0); p = exp2(u); S += p,
// W += p*u (the reference's +eps on the logit is a uniform shift -> softmax
// invariant; its +eps on the message shifts t by 1e-7, below fp16 rounding).
// Records for up to 64 edges preloaded in ONE coalesced load into recv;
// per-edge extraction via v_readlane (SALU) -> scalar-addressed row gathers.
// 16-edge burst pipeline; unmasked steady state; masked tail.

__global__ __launch_bounds__(256) void k_agg(const __half* __restrict__ h16,
                      const unsigned* __restrict__ recs1,
                      const int* __restrict__ offs, const __half* __restrict__ comb16,
                      const int* __restrict__ wstart,
                      __half* __restrict__ t16, int NW) {
    int w = (blockIdx.x * blockDim.x + threadIdx.x) >> 6;
    int lane = threadIdx.x & 63;
    if (w >= NW) return;
    int n0 = wstart[w];       // wave-uniform (s_load)
    int n1 = wstart[w + 1];

    const h2v* hrow = (const h2v*)h16 + lane;    // row r at hrow[r*64]
    const h2v* crow = (const h2v*)comb16 + lane;
    const h2v zero2 = (h2v)(_Float16)0;

#pragma unroll 1
    for (int nid = n0; nid < n1; ++nid) {
        int su = offs[nid];       // wave-uniform
        int eu = offs[nid + 1];
        h2v hm2 = hrow[nid * 64];  // scaled self row
        float hsx = (float)hm2[0], hsy = (float)hm2[1];
        if (su >= eu) {  // empty segment: m = 0; descale
            ((__half2*)t16)[nid * 64 + lane] =
                __floats2half2_rn(hsx * INV_L2E, hsy * INV_L2E);
            continue;
        }
        float Sx = 0.f, Sy = 0.f, Wx = 0.f, Wy = 0.f;
        h2v hq[16], cq[16];
        int e0 = su;
        do {
            int lastc = (eu < e0 + 64) ? eu : e0 + 64;  // chunk end (uniform)
            int last = lastc - 1;
            // one coalesced load covers this chunk's records
            int ridx = e0 + lane;
            ridx = (ridx < eu - 1) ? ridx : eu - 1;
            unsigned recv = recs1[ridx];

            auto load4 = [&](int base, int slot) {
#pragma unroll
                for (int i = 0; i < 4; ++i) {
                    int idx = base + i; idx = (idx < last) ? idx : last;
                    unsigned r = __builtin_amdgcn_readlane(recv, idx - e0);
                    int sj = (int)(r & 0x1FFFFu);
                    int cj = (int)(r >> 17);
                    hq[slot * 4 + i] = hrow[sj * 64];   // saddr + lane*4
                    cq[slot * 4 + i] = crow[cj * 64];
                }
            };
            // steady state: all 4 edges live -> no mask
            auto comp4u = [&](int slot) {
#pragma unroll
                for (int i = 0; i < 4; ++i) {
                    h2v m = hq[slot * 4 + i] + cq[slot * 4 + i];   // v_pk_add_f16
                    m = __builtin_elementwise_max(m, zero2);       // v_pk_max_f16
                    float u0 = (float)m[0], u1 = (float)m[1];
                    float px = __builtin_amdgcn_exp2f(u0);
                    float py = __builtin_amdgcn_exp2f(u1);
                    Sx += px; Sy += py;
                    Wx = fmaf(px, u0, Wx);
                    Wy = fmaf(py, u1, Wy);
                }
            };
            // tail: mask p (not u -- avoids 0*inf NaN in the W fma)
            auto comp4m = [&](int gb, int slot) {
#pragma unroll
                for (int i = 0; i < 4; ++i) {
                    h2v m = hq[slot * 4 + i] + cq[slot * 4 + i];
                    m = __builtin_elementwise_max(m, zero2);
                    float u0 = (float)m[0], u1 = (float)m[1];
                    bool valid = (gb + i) < lastc;  // wave-uniform
                    float px = valid ? __builtin_amdgcn_exp2f(u0) : 0.f;
                    float py = valid ? __builtin_amdgcn_exp2f(u1) : 0.f;
                    Sx += px; Sy += py;
                    Wx = fmaf(px, u0, Wx);
                    Wy = fmaf(py, u1, Wy);
                }
            };

            // prime: burst-issue up to 16 gathers (only live groups)
            load4(e0, 0);
            if (e0 + 4  < lastc) load4(e0 + 4, 1);
            if (e0 + 8  < lastc) load4(e0 + 8, 2);
            if (e0 + 12 < lastc) load4(e0 + 12, 3);

            int e = e0;
            for (; e + 16 < lastc; e += 16) {  // steady: all 16 current live
                comp4u(0); comp4u(1); comp4u(2); comp4u(3);
                load4(e + 16, 0); load4(e + 20, 1);
                load4(e + 24, 2); load4(e + 28, 3);
            }
            // tail: slots hold edges e..e+15 (clamped); masked compute
            comp4m(e, 0);
            if (e + 4  < lastc) comp4m(e + 4, 1);
            if (e + 8  < lastc) comp4m(e + 8, 2);
            if (e + 12 < lastc) comp4m(e + 12, 3);

            e0 = lastc;
        } while (e0 < eu);

        // t = (h_scaled + W/S) / L2E   (W,S in base-2 scaled domain)
        float tx = (hsx + Wx / (Sx + 1e-16f)) * INV_L2E;
        float ty = (hsy + Wy / (Sy + 1e-16f)) * INV_L2E;
        ((__half2*)t16)[nid * 64 + lane] = __floats2half2_rn(tx, ty);
    }
}

// ------------------------- MFMA GEMM + fused LN(+ReLU) ---------------------
// D[f][node] = sum_k Wt16[f][k] * A16[node][k] via v_mfma_f32_16x16x32_f16.
// C/D: col(lane&15)=node, row(quad*4+reg)=f -> lane holds one node's feats;
// LN = per-lane sum + shfl_xor(16,32). No LDS, no barriers.
// MODE 0: write hres16 = o (fp16, unscaled) and h16 = fp16(L2E*relu(LN(o))).
// MODE 1: write out = LN(o) fp32.

template <int MODE>
__global__ __launch_bounds__(256) void k_gemm(const __half* __restrict__ A16,
                                              const __half* __restrict__ Wt16,
                                              const float* __restrict__ bl,
                                              const __half* __restrict__ res16,
                                              __half* __restrict__ hres16,
                                              const float* __restrict__ g,
                                              const float* __restrict__ bta,
                                              __half* __restrict__ h16,
                                              float* __restrict__ out,
                                              int N, int useRes) {
    int lane = threadIdx.x & 63;
    int wave = threadIdx.x >> 6;
    int quad = lane >> 4, col = lane & 15;
    int node = blockIdx.x * 64 + wave * 16 + col;
    bool nok = node < N;
    int nc = nok ? node : N - 1;  // clamp (row N-1 is valid data)

    const __half* arow = A16 + (size_t)nc * 128;
    half8 bfrag[4];
#pragma unroll
    for (int ks = 0; ks < 4; ++ks)
        bfrag[ks] = *(const half8*)(arow + ks * 32 + quad * 8);

    floatx4 acc[8];
#pragma unroll
    for (int ft = 0; ft < 8; ++ft) acc[ft] = (floatx4){0.f, 0.f, 0.f, 0.f};

#pragma unroll
    for (int ft = 0; ft < 8; ++ft) {
        const __half* wrow = Wt16 + (size_t)(ft * 16 + col) * 128;  // A-op: m=f
#pragma unroll
        for (int ks = 0; ks < 4; ++ks) {
            half8 afrag = *(const half8*)(wrow + ks * 32 + quad * 8);
            acc[ft] = __builtin_amdgcn_mfma_f32_16x16x32_f16(afrag, bfrag[ks],
                                                             acc[ft], 0, 0, 0);
        }
    }

    float s = 0.f, ss = 0.f;
#pragma unroll
    for (int ft = 0; ft < 8; ++ft) {
        int f0 = ft * 16 + quad * 4;  // 4 consecutive features per lane
        float4 bb = *(const float4*)(bl + f0);
        float o0 = acc[ft][0] + bb.x, o1 = acc[ft][1] + bb.y;
        float o2 = acc[ft][2] + bb.z, o3 = acc[ft][3] + bb.w;
        if (useRes) {
            uint2 rr = *(const uint2*)(res16 + (size_t)nc * 128 + f0);
            __half2 r01 = *(__half2*)&rr.x, r23 = *(__half2*)&rr.y;
            o0 += __low2float(r01); o1 += __high2float(r01);
            o2 += __low2float(r23); o3 += __high2float(r23);
        }
        acc[ft][0] = o0; acc[ft][1] = o1; acc[ft][2] = o2; acc[ft][3] = o3;
        s += (o0 + o1) + (o2 + o3);
        ss += fmaf(o0, o0, o1 * o1) + fmaf(o2, o2, o3 * o3);
        if (MODE == 0 && nok) {
            __half2 h01 = __floats2half2_rn(o0, o1);
            __half2 h23 = __floats2half2_rn(o2, o3);
            uint2 pk = make_uint2(*(unsigned*)&h01, *(unsigned*)&h23);
            *(uint2*)(hres16 + (size_t)node * 128 + f0) = pk;
        }
    }
    s += __shfl_xor(s, 16, 64);  ss += __shfl_xor(ss, 16, 64);
    s += __shfl_xor(s, 32, 64);  ss += __shfl_xor(ss, 32, 64);
    float mu = s * (1.f / 128.f);
    float var = ss * (1.f / 128.f) - mu * mu;
    float rs = rsqrtf(var + 1e-5f);

#pragma unroll
    for (int ft = 0; ft < 8; ++ft) {
        int f0 = ft * 16 + quad * 4;
        float4 gg = *(const float4*)(g + f0);
        float4 bt = *(const float4*)(bta + f0);
        float l0 = (acc[ft][0] - mu) * rs * gg.x + bt.x;
        float l1 = (acc[ft][1] - mu) * rs * gg.y + bt.y;
        float l2 = (acc[ft][2] - mu) * rs * gg.z + bt.z;
        float l3 = (acc[ft][3] - mu) * rs * gg.w + bt.w;
        if (MODE == 0) {
            l0 = fmaxf(l0, 0.f); l1 = fmaxf(l1, 0.f);
            l2 = fmaxf(l2, 0.f); l3 = fmaxf(l3, 0.f);
            if (nok) {
                __half2 h01 = __floats2half2_rn(l0 * L2E, l1 * L2E);
                __half2 h23 = __floats2half2_rn(l2 * L2E, l3 * L2E);
                uint2 pk = make_uint2(*(unsigned*)&h01, *(unsigned*)&h23);
                *(uint2*)(h16 + (size_t)node * 128 + f0) = pk;
            }
        } else {
            if (nok)
                *(float4*)(out + (size_t)node * 128 + f0) =
                    make_float4(l0, l1, l2, l3);
        }
    }
}

// ------------------------- Launch -------------------------

extern "C" void kernel_launch(void* const* d_in, const int* in_sizes, int n_in,
                              void* d_out, int out_size, void* d_ws, size_t ws_size,
                              hipStream_t stream) {
    const int*   x    = (const int*)d_in[0];
    const int*   ei   = (const int*)d_in[1];
    const int*   attr = (const int*)d_in[2];
    const float* aemb = (const float*)d_in[3];
    const float* bemb = (const float*)d_in[4];
    const float* Wf   = (const float*)d_in[5];
    const float* bf   = (const float*)d_in[6];
    const float* gam  = (const float*)d_in[7];
    const float* bet  = (const float*)d_in[8];
    float* out = (float*)d_out;

    const int N = in_sizes[0] / NA;        // 50000
    const int E = in_sizes[1] / 2;         // 625000
    const int L = in_sizes[5] / (D * D);   // 7
    const int NW = (E + CEDGE - 1) / CEDGE;  // ~19532 waves

    char* ws = (char*)d_ws;
    size_t o = 0;
    auto carve = [&](size_t bytes) -> void* {
        void* p = (void*)(ws + o);
        o += (bytes + 255) & ~(size_t)255;
        return p;
    };
    __half* hres16 = (__half*)carve((size_t)N * D * 2);  // fp16 residual chain
    __half* h16    = (__half*)carve((size_t)N * D * 2);  // fp16 gather table (x L2E)
    __half* t16    = (__half*)carve((size_t)N * D * 2);  // fp16 agg output
    unsigned* recs1 = (unsigned*)carve((size_t)E * 4);   // packed records
    __half* comb16 = (__half*)carve(512 * D * 2);
    __half* Wt16   = (__half*)carve((size_t)L * D * D * 2);
    int*    deg    = (int*)carve((size_t)N * 4);
    int*    cur    = (int*)carve((size_t)N * 4);
    int*    offs   = (int*)carve((size_t)(N + 1) * 4);
    int*    wstart = (int*)carve((size_t)(NW + 1) * 4);
    int*    bsum   = (int*)carve(4096);
    int*    bexc   = (int*)carve(4096);

    const int* src = ei;
    const int* dst = ei + E;

    hipMemsetAsync(deg, 0, (size_t)N * 4, stream);
    hipMemsetAsync(cur, 0, (size_t)N * 4, stream);

    int ebl = (E + 255) / 256;
    int nbl = (N + 255) / 256;  // 196 (<=256 required by k_scan_b)
    k_comb<<<64, 256, 0, stream>>>(bemb, comb16);
    int wtot = L * D * D;
    k_wt<<<(wtot + 255) / 256, 256, 0, stream>>>(Wf, Wt16, wtot);
    k_hist<<<ebl, 256, 0, stream>>>(dst, deg, E);
    k_scan_a<<<nbl, 256, 0, stream>>>(deg, offs, bsum, N);
    k_scan_b<<<1, 256, 0, stream>>>(bsum, bexc, nbl);
    k_scan_c<<<nbl, 256, 0, stream>>>(offs, bexc, N);
    k_fill<<<ebl, 256, 0, stream>>>(src, dst, attr, offs, cur, recs1, E);
    k_part<<<nbl, 256, 0, stream>>>(offs, wstart, N, NW);

    int wbl = (N * 64 + 255) / 256;  // wave per node (encoder only)
    k_atom<<<wbl, 256, 0, stream>>>(x, aemb, h16, N);

    int abl = (NW * 64 + 255) / 256;  // edge-balanced agg waves
    int gbl = (N + 63) / 64;          // 782 blocks, 64 nodes each
    for (int l = 0; l < L; ++l) {
        k_agg<<<abl, 256, 0, stream>>>(h16, recs1, offs, comb16, wstart, t16, NW);
        if (l == L - 1) {
            k_gemm<1><<<gbl, 256, 0, stream>>>(t16, Wt16 + l * D * D, bf + l * D,
                                               hres16, hres16,
                                               gam + l * D, bet + l * D, h16, out,
                                               N, 1);
        } else {
            k_gemm<0><<<gbl, 256, 0, stream>>>(t16, Wt16 + l * D * D, bf + l * D,
                                               hres16, hres16,
                                               gam + l * D, bet + l * D, h16, out,
                                               N, l > 0 ? 1 : 0);
        }
    }
}

// Round 5
// 596.263 us; speedup vs baseline: 1.2688x; 1.1170x over previous
//
#include <hip/hip_runtime.h>
#include <hip/hip_fp16.h>
#include <math.h>

// DeeperGCN on MI355X. N=50000, E=625000, D=128, L=7.
// fp16 inter-kernel streams; gather tables (h16, comb16) PRE-SCALED by
// log2(e) so the aggregation logit is a direct packed-fp16 add/max chain;
// CSR-by-dst build; degree-sorted node order (LDS-aggregated counting sort);
// k_agg: wave per node, 64-lane rows, packed u32 records preloaded 64-wide
// + v_readlane extraction, 16-edge burst gather pipeline;
// k_gemm: FEATURE-SPLIT MFMA GEMM -- each wave does 16 nodes x 64 feats
// (half row), wave pairs exchange LN partials via 512B LDS; 2x wave count
// vs full-row version (6250 waves, 6.1 blocks/CU) to attack latency-bound
// epilogue; fused bias/res/LN(+ReLU).

constexpr int D = 128;
constexpr int NA = 9;   // atom feats
constexpr int NB = 3;   // bond feats
constexpr float L2E = 1.4426950408889634f;   // log2(e)
constexpr float INV_L2E = 0.6931471805599453f;

using half8  = __attribute__((ext_vector_type(8))) _Float16;
using h2v    = __attribute__((ext_vector_type(2))) _Float16;
using floatx4 = __attribute__((ext_vector_type(4))) float;

// ------------------------- CSR build -------------------------

__global__ void k_hist(const int* __restrict__ dst, int* __restrict__ deg, int E) {
    int e = blockIdx.x * 256 + threadIdx.x;
    if (e < E) atomicAdd(&deg[dst[e]], 1);
}

__global__ void k_scan_a(const int* __restrict__ deg, int* __restrict__ offs,
                         int* __restrict__ bsum, int N) {
    __shared__ int s[256];
    int i = blockIdx.x * 256 + threadIdx.x;
    int v = (i < N) ? deg[i] : 0;
    s[threadIdx.x] = v;
    __syncthreads();
    for (int d = 1; d < 256; d <<= 1) {
        int add = (threadIdx.x >= d) ? s[threadIdx.x - d] : 0;
        __syncthreads();
        s[threadIdx.x] += add;
        __syncthreads();
    }
    if (i < N) offs[i + 1] = s[threadIdx.x];
    if (threadIdx.x == 255) bsum[blockIdx.x] = s[255];
    if (i == 0) offs[0] = 0;
}

// nb must be <= 256 (N=50000 -> nb=196)
__global__ void k_scan_b(const int* __restrict__ bsum, int* __restrict__ bexc, int nb) {
    __shared__ int s[256];
    int t = threadIdx.x;
    int v = (t < nb) ? bsum[t] : 0;
    s[t] = v;
    __syncthreads();
    for (int d = 1; d < 256; d <<= 1) {
        int add = (t >= d) ? s[t - d] : 0;
        __syncthreads();
        s[t] += add;
        __syncthreads();
    }
    if (t < nb) bexc[t] = s[t] - v;  // exclusive block prefix
}

__global__ void k_scan_c(int* __restrict__ offs, const int* __restrict__ bexc, int N) {
    int i = blockIdx.x * 256 + threadIdx.x;
    if (i < N) offs[i + 1] += bexc[blockIdx.x];
}

// packed record: src (17 bits, N<2^17) | cidx<<17 (9 bits)
__global__ void k_fill(const int* __restrict__ src, const int* __restrict__ dst,
                       const int* __restrict__ attr, const int* __restrict__ offs,
                       int* __restrict__ cur, unsigned* __restrict__ recs1, int E) {
    int e = blockIdx.x * 256 + threadIdx.x;
    if (e >= E) return;
    int d = dst[e];
    int pos = offs[d] + atomicAdd(&cur[d], 1);
    unsigned cidx = (unsigned)(attr[e * 3] * 64 + attr[e * 3 + 1] * 8 + attr[e * 3 + 2]);
    recs1[pos] = (unsigned)src[e] | (cidx << 17);
}

// ---------------- degree counting sort (descending), LDS-aggregated --------

__global__ void k_dhist(const int* __restrict__ deg, int* __restrict__ dbin, int N) {
    __shared__ int lb[64];
    int t = threadIdx.x;
    if (t < 64) lb[t] = 0;
    __syncthreads();
    int i = blockIdx.x * 256 + t;
    if (i < N) {
        int d = deg[i]; d = d < 63 ? d : 63;
        atomicAdd(&lb[63 - d], 1);  // LDS atomic (bin 0 = heaviest)
    }
    __syncthreads();
    if (t < 64 && lb[t] > 0) atomicAdd(&dbin[t], lb[t]);
}

__global__ void k_dscan(const int* __restrict__ dbin, int* __restrict__ doff) {
    if (threadIdx.x == 0) {
        int acc = 0;
        for (int b = 0; b < 64; ++b) { doff[b] = acc; acc += dbin[b]; }
    }
}

__global__ void k_dfill(const int* __restrict__ deg, const int* __restrict__ doff,
                        int* __restrict__ dcur, int* __restrict__ perm, int N) {
    __shared__ int lc[64], lbase[64];
    int t = threadIdx.x;
    if (t < 64) lc[t] = 0;
    __syncthreads();
    int i = blockIdx.x * 256 + t;
    int b = 0, rank = 0;
    if (i < N) {
        int d = deg[i]; d = d < 63 ? d : 63;
        b = 63 - d;
        rank = atomicAdd(&lc[b], 1);  // LDS rank within block
    }
    __syncthreads();
    if (t < 64 && lc[t] > 0) lbase[t] = atomicAdd(&dcur[t], lc[t]);  // reserve
    __syncthreads();
    if (i < N) perm[doff[b] + lbase[b] + rank] = i;
}

// comb16[c][d] = fp16(L2E * (b0[c>>6][d] + b1[(c>>3)&7][d] + b2[c&7][d]))
__global__ void k_comb(const float* __restrict__ bemb, __half* __restrict__ comb16) {
    int gid = blockIdx.x * 256 + threadIdx.x;  // 512*32 float4s
    int c = gid >> 5, q = gid & 31;
    int a0 = c >> 6, a1 = (c >> 3) & 7, a2 = c & 7;
    float4 v0 = *(const float4*)(bemb + (a0)*D + q * 4);
    float4 v1 = *(const float4*)(bemb + (8 + a1) * D + q * 4);
    float4 v2 = *(const float4*)(bemb + (16 + a2) * D + q * 4);
    __half2* c2 = (__half2*)comb16;
    c2[c * 64 + q * 2]     = __floats2half2_rn(L2E * (v0.x + v1.x + v2.x),
                                               L2E * (v0.y + v1.y + v2.y));
    c2[c * 64 + q * 2 + 1] = __floats2half2_rn(L2E * (v0.z + v1.z + v2.z),
                                               L2E * (v0.w + v1.w + v2.w));
}

// Wt16[l][f][k] = fp16(W[l][k][f])  -- K-major transposed fp16 weights
__global__ void k_wt(const float* __restrict__ W, __half* __restrict__ Wt16, int total) {
    int o = blockIdx.x * 256 + threadIdx.x;
    if (o >= total) return;
    int l = o >> 14;          // /(128*128)
    int rem = o & 16383;
    int f = rem >> 7, k = rem & 127;
    Wt16[o] = __float2half_rn(W[(l << 14) + k * 128 + f]);
}

// ------------------------- Atom encoder (scaled h16) -------------------------

__global__ void k_atom(const int* __restrict__ x, const float* __restrict__ aemb,
                       __half* __restrict__ h16, int N) {
    int wid = (blockIdx.x * blockDim.x + threadIdx.x) >> 6;
    int lane = threadIdx.x & 63;
    if (wid >= N) return;
    const int* xr = x + wid * NA;
    float ax = 0.f, ay = 0.f;
#pragma unroll
    for (int f = 0; f < NA; ++f) {
        int v = xr[f];  // wave-uniform broadcast
        const float2 e = *(const float2*)(aemb + (f * 64 + v) * D + 2 * lane);
        ax += e.x; ay += e.y;
    }
    ((__half2*)h16)[wid * 64 + lane] = __floats2half2_rn(ax * L2E, ay * L2E);
}

// ------------------------- Aggregation ------------------------------------
// wave per node (degree-sorted order); t16[n] = (h16s[n] + W/S) / L2E.
// Tables pre-scaled by L2E: logit u = max(h'+c',0); p = exp2(u); S += p,
// W += p*u (reference's +eps on the logit is a uniform shift -> softmax
// invariant; its +eps on the message shifts t by 1e-7, below fp16 rounding).
// Records for up to 64 edges preloaded in ONE coalesced load into recv;
// per-edge extraction via v_readlane (SALU) -> scalar-addressed row gathers.
// 16-edge burst pipeline; unmasked steady state; masked tail.

__global__ __launch_bounds__(256) void k_agg(const __half* __restrict__ h16,
                      const unsigned* __restrict__ recs1,
                      const int* __restrict__ offs, const __half* __restrict__ comb16,
                      const int* __restrict__ perm,
                      __half* __restrict__ t16, int N) {
    int wid = (blockIdx.x * blockDim.x + threadIdx.x) >> 6;
    int lane = threadIdx.x & 63;
    if (wid >= N) return;
    int nid = perm[wid];  // wave-uniform
    int su = __builtin_amdgcn_readfirstlane(offs[nid]);
    int eu = __builtin_amdgcn_readfirstlane(offs[nid + 1]);
    h2v hm2 = ((const h2v*)h16)[nid * 64 + lane];  // scaled self row
    float hsx = (float)hm2[0], hsy = (float)hm2[1];
    if (su >= eu) {  // empty segment: m = 0; descale
        ((__half2*)t16)[nid * 64 + lane] =
            __floats2half2_rn(hsx * INV_L2E, hsy * INV_L2E);
        return;
    }
    float Sx = 0.f, Sy = 0.f, Wx = 0.f, Wy = 0.f;

    const h2v* hrow = (const h2v*)h16 + lane;    // row r at hrow[r*64]
    const h2v* crow = (const h2v*)comb16 + lane;
    const h2v zero2 = (h2v)(_Float16)0;

    h2v hq[16], cq[16];

    int e0 = su;
    do {
        int lastc = (eu < e0 + 64) ? eu : e0 + 64;  // chunk end (uniform)
        int last = lastc - 1;
        // one coalesced load covers this chunk's records
        int ridx = e0 + lane;
        ridx = (ridx < eu - 1) ? ridx : eu - 1;
        unsigned recv = recs1[ridx];

        auto load4 = [&](int base, int slot) {
#pragma unroll
            for (int i = 0; i < 4; ++i) {
                int idx = base + i; idx = (idx < last) ? idx : last;
                unsigned r = __builtin_amdgcn_readlane(recv, idx - e0);  // SGPR
                int sj = (int)(r & 0x1FFFFu);
                int cj = (int)(r >> 17);
                hq[slot * 4 + i] = hrow[sj * 64];   // saddr + lane*4
                cq[slot * 4 + i] = crow[cj * 64];
            }
        };
        // steady state: all 4 edges live -> no mask
        auto comp4u = [&](int slot) {
#pragma unroll
            for (int i = 0; i < 4; ++i) {
                h2v m = hq[slot * 4 + i] + cq[slot * 4 + i];   // v_pk_add_f16
                m = __builtin_elementwise_max(m, zero2);       // v_pk_max_f16
                float u0 = (float)m[0], u1 = (float)m[1];
                float px = __builtin_amdgcn_exp2f(u0);
                float py = __builtin_amdgcn_exp2f(u1);
                Sx += px; Sy += py;
                Wx = fmaf(px, u0, Wx);
                Wy = fmaf(py, u1, Wy);
            }
        };
        // tail: mask p (not u -- avoids 0*inf NaN in the W fma)
        auto comp4m = [&](int gb, int slot) {
#pragma unroll
            for (int i = 0; i < 4; ++i) {
                h2v m = hq[slot * 4 + i] + cq[slot * 4 + i];
                m = __builtin_elementwise_max(m, zero2);
                float u0 = (float)m[0], u1 = (float)m[1];
                bool valid = (gb + i) < eu;  // wave-uniform
                float px = valid ? __builtin_amdgcn_exp2f(u0) : 0.f;
                float py = valid ? __builtin_amdgcn_exp2f(u1) : 0.f;
                Sx += px; Sy += py;
                Wx = fmaf(px, u0, Wx);
                Wy = fmaf(py, u1, Wy);
            }
        };

        // prime: burst-issue up to 16 gathers (only live groups)
        load4(e0, 0);
        if (e0 + 4  < lastc) load4(e0 + 4, 1);
        if (e0 + 8  < lastc) load4(e0 + 8, 2);
        if (e0 + 12 < lastc) load4(e0 + 12, 3);

        int e = e0;
        for (; e + 16 < lastc; e += 16) {  // steady: all 16 current edges live
            comp4u(0); comp4u(1); comp4u(2); comp4u(3);
            load4(e + 16, 0); load4(e + 20, 1); load4(e + 24, 2); load4(e + 28, 3);
        }
        // tail: slots hold edges e..e+15 (clamped); masked compute
        comp4m(e, 0);
        if (e + 4  < lastc) comp4m(e + 4, 1);
        if (e + 8  < lastc) comp4m(e + 8, 2);
        if (e + 12 < lastc) comp4m(e + 12, 3);

        e0 = lastc;
    } while (e0 < eu);

    // t = (h_scaled + W/S) / L2E   (W,S in base-2 scaled domain)
    float tx = (hsx + Wx / (Sx + 1e-16f)) * INV_L2E;
    float ty = (hsy + Wy / (Sy + 1e-16f)) * INV_L2E;
    ((__half2*)t16)[nid * 64 + lane] = __floats2half2_rn(tx, ty);
}

// ------------------- Feature-split MFMA GEMM + fused LN(+ReLU) -------------
// Wave = 16 nodes x 64 feats (half row). Block = 4 waves = 32 nodes.
// wave: grp = wave>>1 (node group), half = wave&1 (feature half).
// D[f][node] = sum_k Wt16[f][k] * A16[node][k] via v_mfma_f32_16x16x32_f16;
// C/D: col(lane&15)=node, row(quad*4+reg)=f. LN: per-wave half-sums via
// shfl_xor(16,32), halves exchanged through 512B LDS (one barrier).
// MODE 0: hres16 = o (fp16); h16 = fp16(L2E*relu(LN(o))). MODE 1: out fp32.

template <int MODE>
__global__ __launch_bounds__(256) void k_gemm(const __half* __restrict__ A16,
                                              const __half* __restrict__ Wt16,
                                              const float* __restrict__ bl,
                                              const __half* __restrict__ res16,
                                              __half* __restrict__ hres16,
                                              const float* __restrict__ g,
                                              const float* __restrict__ bta,
                                              __half* __restrict__ h16,
                                              float* __restrict__ out,
                                              int N, int useRes) {
    __shared__ float2 sm[2][2][16];
    int lane = threadIdx.x & 63;
    int wave = threadIdx.x >> 6;
    int grp = wave >> 1, half = wave & 1;
    int quad = lane >> 4, col = lane & 15;
    int node = blockIdx.x * 32 + grp * 16 + col;
    bool nok = node < N;
    int nc = nok ? node : N - 1;  // clamp (row N-1 is valid data)

    const __half* arow = A16 + (size_t)nc * 128;
    half8 bfrag[4];
#pragma unroll
    for (int ks = 0; ks < 4; ++ks)
        bfrag[ks] = *(const half8*)(arow + ks * 32 + quad * 8);

    // prefetch residual half-row (overlaps with MFMA)
    uint2 rr[4];
    if (useRes) {
#pragma unroll
        for (int ft2 = 0; ft2 < 4; ++ft2) {
            int f0 = (half * 4 + ft2) * 16 + quad * 4;
            rr[ft2] = *(const uint2*)(res16 + (size_t)nc * 128 + f0);
        }
    }

    floatx4 acc[4];
#pragma unroll
    for (int ft2 = 0; ft2 < 4; ++ft2) acc[ft2] = (floatx4){0.f, 0.f, 0.f, 0.f};

#pragma unroll
    for (int ft2 = 0; ft2 < 4; ++ft2) {
        const __half* wrow = Wt16 + (size_t)((half * 4 + ft2) * 16 + col) * 128;
#pragma unroll
        for (int ks = 0; ks < 4; ++ks) {
            half8 afrag = *(const half8*)(wrow + ks * 32 + quad * 8);
            acc[ft2] = __builtin_amdgcn_mfma_f32_16x16x32_f16(afrag, bfrag[ks],
                                                              acc[ft2], 0, 0, 0);
        }
    }

    float s = 0.f, ss = 0.f;
#pragma unroll
    for (int ft2 = 0; ft2 < 4; ++ft2) {
        int f0 = (half * 4 + ft2) * 16 + quad * 4;
        float4 bb = *(const float4*)(bl + f0);
        float o0 = acc[ft2][0] + bb.x, o1 = acc[ft2][1] + bb.y;
        float o2 = acc[ft2][2] + bb.z, o3 = acc[ft2][3] + bb.w;
        if (useRes) {
            __half2 r01 = *(__half2*)&rr[ft2].x, r23 = *(__half2*)&rr[ft2].y;
            o0 += __low2float(r01); o1 += __high2float(r01);
            o2 += __low2float(r23); o3 += __high2float(r23);
        }
        acc[ft2][0] = o0; acc[ft2][1] = o1; acc[ft2][2] = o2; acc[ft2][3] = o3;
        s += (o0 + o1) + (o2 + o3);
        ss += fmaf(o0, o0, o1 * o1) + fmaf(o2, o2, o3 * o3);
        if (MODE == 0 && nok) {
            __half2 h01 = __floats2half2_rn(o0, o1);
            __half2 h23 = __floats2half2_rn(o2, o3);
            uint2 pk = make_uint2(*(unsigned*)&h01, *(unsigned*)&h23);
            *(uint2*)(hres16 + (size_t)node * 128 + f0) = pk;
        }
    }
    // reduce over quads -> half-row sums (all lanes hold their col's sum)
    s += __shfl_xor(s, 16, 64);  ss += __shfl_xor(ss, 16, 64);
    s += __shfl_xor(s, 32, 64);  ss += __shfl_xor(ss, 32, 64);
    if (quad == 0) sm[grp][half][col] = make_float2(s, ss);
    __syncthreads();
    float2 oth = sm[grp][half ^ 1][col];
    float st = s + oth.x, sst = ss + oth.y;
    float mu = st * (1.f / 128.f);
    float var = sst * (1.f / 128.f) - mu * mu;
    float rs = rsqrtf(var + 1e-5f);

#pragma unroll
    for (int ft2 = 0; ft2 < 4; ++ft2) {
        int f0 = (half * 4 + ft2) * 16 + quad * 4;
        float4 gg = *(const float4*)(g + f0);
        float4 bt = *(const float4*)(bta + f0);
        float l0 = (acc[ft2][0] - mu) * rs * gg.x + bt.x;
        float l1 = (acc[ft2][1] - mu) * rs * gg.y + bt.y;
        float l2 = (acc[ft2][2] - mu) * rs * gg.z + bt.z;
        float l3 = (acc[ft2][3] - mu) * rs * gg.w + bt.w;
        if (MODE == 0) {
            l0 = fmaxf(l0, 0.f); l1 = fmaxf(l1, 0.f);
            l2 = fmaxf(l2, 0.f); l3 = fmaxf(l3, 0.f);
            if (nok) {
                __half2 h01 = __floats2half2_rn(l0 * L2E, l1 * L2E);
                __half2 h23 = __floats2half2_rn(l2 * L2E, l3 * L2E);
                uint2 pk = make_uint2(*(unsigned*)&h01, *(unsigned*)&h23);
                *(uint2*)(h16 + (size_t)node * 128 + f0) = pk;
            }
        } else {
            if (nok)
                *(float4*)(out + (size_t)node * 128 + f0) =
                    make_float4(l0, l1, l2, l3);
        }
    }
}

// ------------------------- Launch -------------------------

extern "C" void kernel_launch(void* const* d_in, const int* in_sizes, int n_in,
                              void* d_out, int out_size, void* d_ws, size_t ws_size,
                              hipStream_t stream) {
    const int*   x    = (const int*)d_in[0];
    const int*   ei   = (const int*)d_in[1];
    const int*   attr = (const int*)d_in[2];
    const float* aemb = (const float*)d_in[3];
    const float* bemb = (const float*)d_in[4];
    const float* Wf   = (const float*)d_in[5];
    const float* bf   = (const float*)d_in[6];
    const float* gam  = (const float*)d_in[7];
    const float* bet  = (const float*)d_in[8];
    float* out = (float*)d_out;

    const int N = in_sizes[0] / NA;        // 50000
    const int E = in_sizes[1] / 2;         // 625000
    const int L = in_sizes[5] / (D * D);   // 7

    char* ws = (char*)d_ws;
    size_t o = 0;
    auto carve = [&](size_t bytes) -> void* {
        void* p = (void*)(ws + o);
        o += (bytes + 255) & ~(size_t)255;
        return p;
    };
    __half* hres16 = (__half*)carve((size_t)N * D * 2);  // fp16 residual chain
    __half* h16    = (__half*)carve((size_t)N * D * 2);  // fp16 gather table (x L2E)
    __half* t16    = (__half*)carve((size_t)N * D * 2);  // fp16 agg output
    unsigned* recs1 = (unsigned*)carve((size_t)E * 4);   // packed records
    __half* comb16 = (__half*)carve(512 * D * 2);
    __half* Wt16   = (__half*)carve((size_t)L * D * D * 2);
    int*    deg    = (int*)carve((size_t)N * 4);
    int*    cur    = (int*)carve((size_t)N * 4);
    int*    offs   = (int*)carve((size_t)(N + 1) * 4);
    int*    perm   = (int*)carve((size_t)N * 4);
    int*    dbin   = (int*)carve(256);
    int*    doff   = (int*)carve(256);
    int*    dcur   = (int*)carve(256);
    int*    bsum   = (int*)carve(4096);
    int*    bexc   = (int*)carve(4096);

    const int* src = ei;
    const int* dst = ei + E;

    hipMemsetAsync(deg, 0, (size_t)N * 4, stream);
    hipMemsetAsync(cur, 0, (size_t)N * 4, stream);
    hipMemsetAsync(dbin, 0, 256, stream);
    hipMemsetAsync(dcur, 0, 256, stream);

    int ebl = (E + 255) / 256;
    int nbl = (N + 255) / 256;  // 196 (<=256 required by k_scan_b)
    k_comb<<<64, 256, 0, stream>>>(bemb, comb16);
    int wtot = L * D * D;
    k_wt<<<(wtot + 255) / 256, 256, 0, stream>>>(Wf, Wt16, wtot);
    k_hist<<<ebl, 256, 0, stream>>>(dst, deg, E);
    k_scan_a<<<nbl, 256, 0, stream>>>(deg, offs, bsum, N);
    k_scan_b<<<1, 256, 0, stream>>>(bsum, bexc, nbl);
    k_scan_c<<<nbl, 256, 0, stream>>>(offs, bexc, N);
    k_fill<<<ebl, 256, 0, stream>>>(src, dst, attr, offs, cur, recs1, E);
    k_dhist<<<nbl, 256, 0, stream>>>(deg, dbin, N);
    k_dscan<<<1, 64, 0, stream>>>(dbin, doff);
    k_dfill<<<nbl, 256, 0, stream>>>(deg, doff, dcur, perm, N);

    int wbl = (N * 64 + 255) / 256;  // wave per node
    k_atom<<<wbl, 256, 0, stream>>>(x, aemb, h16, N);

    int gbl = (N + 31) / 32;  // 1563 blocks, 32 nodes each (feature-split)
    for (int l = 0; l < L; ++l) {
        k_agg<<<wbl, 256, 0, stream>>>(h16, recs1, offs, comb16, perm, t16, N);
        if (l == L - 1) {
            k_gemm<1><<<gbl, 256, 0, stream>>>(t16, Wt16 + l * D * D, bf + l * D,
                                               hres16, hres16,
                                               gam + l * D, bet + l * D, h16, out,
                                               N, 1);
        } else {
            k_gemm<0><<<gbl, 256, 0, stream>>>(t16, Wt16 + l * D * D, bf + l * D,
                                               hres16, hres16,
                                               gam + l * D, bet + l * D, h16, out,
                                               N, l > 0 ? 1 : 0);
        }
    }
}

// Round 6
// 586.484 us; speedup vs baseline: 1.2900x; 1.0167x over previous
//
#include <hip/hip_runtime.h>
#include <hip/hip_fp16.h>
#include <math.h>

// DeeperGCN on MI355X. N=50000, E=625000, D=128, L=7.
// fp16 inter-kernel streams; gather tables (h16, comb16) PRE-SCALED by
// log2(e) so the aggregation logit is a direct packed-fp16 add/max chain;
// CSR-by-dst build; degree-sorted node order (LDS-aggregated counting sort);
// COMPRESSED setup chain (memsets folded into k_comb; dhist fused into
// scan_c; dscan folded into k_fill block 0) -- 9 setup dispatches vs 14;
// k_agg: wave per node, 64-lane rows, packed u32 records preloaded 64-wide
// + v_readlane extraction, 16-edge burst gather pipeline;
// k_gemm: feature-split MFMA GEMM (wave = 16 nodes x 64 feats, LN partials
// exchanged via 512B LDS) with fused bias/res/LN(+ReLU).

constexpr int D = 128;
constexpr int NA = 9;   // atom feats
constexpr int NB = 3;   // bond feats
constexpr float L2E = 1.4426950408889634f;   // log2(e)
constexpr float INV_L2E = 0.6931471805599453f;

using half8  = __attribute__((ext_vector_type(8))) _Float16;
using h2v    = __attribute__((ext_vector_type(2))) _Float16;
using floatx4 = __attribute__((ext_vector_type(4))) float;

// ------------------------- CSR build -------------------------

__global__ void k_hist(const int* __restrict__ dst, int* __restrict__ deg, int E) {
    int e = blockIdx.x * 256 + threadIdx.x;
    if (e < E) atomicAdd(&deg[dst[e]], 1);
}

__global__ void k_scan_a(const int* __restrict__ deg, int* __restrict__ offs,
                         int* __restrict__ bsum, int N) {
    __shared__ int s[256];
    int i = blockIdx.x * 256 + threadIdx.x;
    int v = (i < N) ? deg[i] : 0;
    s[threadIdx.x] = v;
    __syncthreads();
    for (int d = 1; d < 256; d <<= 1) {
        int add = (threadIdx.x >= d) ? s[threadIdx.x - d] : 0;
        __syncthreads();
        s[threadIdx.x] += add;
        __syncthreads();
    }
    if (i < N) offs[i + 1] = s[threadIdx.x];
    if (threadIdx.x == 255) bsum[blockIdx.x] = s[255];
    if (i == 0) offs[0] = 0;
}

// nb must be <= 256 (N=50000 -> nb=196)
__global__ void k_scan_b(const int* __restrict__ bsum, int* __restrict__ bexc, int nb) {
    __shared__ int s[256];
    int t = threadIdx.x;
    int v = (t < nb) ? bsum[t] : 0;
    s[t] = v;
    __syncthreads();
    for (int d = 1; d < 256; d <<= 1) {
        int add = (t >= d) ? s[t - d] : 0;
        __syncthreads();
        s[t] += add;
        __syncthreads();
    }
    if (t < nb) bexc[t] = s[t] - v;  // exclusive block prefix
}

// scan_c (finalize offs) fused with dhist (degree histogram; independent data)
__global__ void k_scan_c_dhist(int* __restrict__ offs, const int* __restrict__ bexc,
                               const int* __restrict__ deg, int* __restrict__ dbin,
                               int N) {
    __shared__ int lb[64];
    int t = threadIdx.x;
    if (t < 64) lb[t] = 0;
    __syncthreads();
    int i = blockIdx.x * 256 + t;
    if (i < N) {
        offs[i + 1] += bexc[blockIdx.x];
        int d = deg[i]; d = d < 63 ? d : 63;
        atomicAdd(&lb[63 - d], 1);  // LDS atomic (bin 0 = heaviest)
    }
    __syncthreads();
    if (t < 64 && lb[t] > 0) atomicAdd(&dbin[t], lb[t]);
}

// packed record: src (17 bits, N<2^17) | cidx<<17 (9 bits).
// block 0 / thread 0 additionally runs the 64-entry degree-bin scan (dscan):
// dbin is complete before this kernel launches; doff is only read by k_dfill.
__global__ void k_fill(const int* __restrict__ src, const int* __restrict__ dst,
                       const int* __restrict__ attr, const int* __restrict__ offs,
                       int* __restrict__ cur, unsigned* __restrict__ recs1,
                       const int* __restrict__ dbin, int* __restrict__ doff, int E) {
    int e = blockIdx.x * 256 + threadIdx.x;
    if (e < E) {
        int d = dst[e];
        int pos = offs[d] + atomicAdd(&cur[d], 1);
        unsigned cidx = (unsigned)(attr[e * 3] * 64 + attr[e * 3 + 1] * 8 + attr[e * 3 + 2]);
        recs1[pos] = (unsigned)src[e] | (cidx << 17);
    }
    if (blockIdx.x == 0 && threadIdx.x == 0) {
        int acc = 0;
        for (int b = 0; b < 64; ++b) { doff[b] = acc; acc += dbin[b]; }
    }
}

// ---------------- degree counting sort (descending), LDS-aggregated --------

__global__ void k_dfill(const int* __restrict__ deg, const int* __restrict__ doff,
                        int* __restrict__ dcur, int* __restrict__ perm, int N) {
    __shared__ int lc[64], lbase[64];
    int t = threadIdx.x;
    if (t < 64) lc[t] = 0;
    __syncthreads();
    int i = blockIdx.x * 256 + t;
    int b = 0, rank = 0;
    if (i < N) {
        int d = deg[i]; d = d < 63 ? d : 63;
        b = 63 - d;
        rank = atomicAdd(&lc[b], 1);  // LDS rank within block
    }
    __syncthreads();
    if (t < 64 && lc[t] > 0) lbase[t] = atomicAdd(&dcur[t], lc[t]);  // reserve
    __syncthreads();
    if (i < N) perm[doff[b] + lbase[b] + rank] = i;
}

// comb16[c][d] = fp16(L2E * (b0[c>>6][d] + b1[(c>>3)&7][d] + b2[c&7][d]))
// Also zeroes deg/cur/dbin/dcur (replaces 4 hipMemsetAsync launches).
// Grid must cover max(16384, N) threads.
__global__ void k_comb(const float* __restrict__ bemb, __half* __restrict__ comb16,
                       int* __restrict__ deg, int* __restrict__ cur,
                       int* __restrict__ dbin, int* __restrict__ dcur, int N) {
    int gid = blockIdx.x * 256 + threadIdx.x;
    if (gid < N) { deg[gid] = 0; cur[gid] = 0; }
    if (gid < 64) { dbin[gid] = 0; dcur[gid] = 0; }
    if (gid >= 512 * 32) return;  // 512 combos x 32 float4s
    int c = gid >> 5, q = gid & 31;
    int a0 = c >> 6, a1 = (c >> 3) & 7, a2 = c & 7;
    float4 v0 = *(const float4*)(bemb + (a0)*D + q * 4);
    float4 v1 = *(const float4*)(bemb + (8 + a1) * D + q * 4);
    float4 v2 = *(const float4*)(bemb + (16 + a2) * D + q * 4);
    __half2* c2 = (__half2*)comb16;
    c2[c * 64 + q * 2]     = __floats2half2_rn(L2E * (v0.x + v1.x + v2.x),
                                               L2E * (v0.y + v1.y + v2.y));
    c2[c * 64 + q * 2 + 1] = __floats2half2_rn(L2E * (v0.z + v1.z + v2.z),
                                               L2E * (v0.w + v1.w + v2.w));
}

// Wt16[l][f][k] = fp16(W[l][k][f])  -- K-major transposed fp16 weights
__global__ void k_wt(const float* __restrict__ W, __half* __restrict__ Wt16, int total) {
    int o = blockIdx.x * 256 + threadIdx.x;
    if (o >= total) return;
    int l = o >> 14;          // /(128*128)
    int rem = o & 16383;
    int f = rem >> 7, k = rem & 127;
    Wt16[o] = __float2half_rn(W[(l << 14) + k * 128 + f]);
}

// ------------------------- Atom encoder (scaled h16) -------------------------

__global__ void k_atom(const int* __restrict__ x, const float* __restrict__ aemb,
                       __half* __restrict__ h16, int N) {
    int wid = (blockIdx.x * blockDim.x + threadIdx.x) >> 6;
    int lane = threadIdx.x & 63;
    if (wid >= N) return;
    const int* xr = x + wid * NA;
    float ax = 0.f, ay = 0.f;
#pragma unroll
    for (int f = 0; f < NA; ++f) {
        int v = xr[f];  // wave-uniform broadcast
        const float2 e = *(const float2*)(aemb + (f * 64 + v) * D + 2 * lane);
        ax += e.x; ay += e.y;
    }
    ((__half2*)h16)[wid * 64 + lane] = __floats2half2_rn(ax * L2E, ay * L2E);
}

// ------------------------- Aggregation ------------------------------------
// wave per node (degree-sorted order); t16[n] = (h16s[n] + W/S) / L2E.
// Tables pre-scaled by L2E: logit u = max(h'+c',0); p = exp2(u); S += p,
// W += p*u (reference's +eps on the logit is a uniform shift -> softmax
// invariant; its +eps on the message shifts t by 1e-7, below fp16 rounding).
// Records for up to 64 edges preloaded in ONE coalesced load into recv;
// per-edge extraction via v_readlane (SALU) -> scalar-addressed row gathers.
// 16-edge burst pipeline; unmasked steady state; masked tail.

__global__ __launch_bounds__(256) void k_agg(const __half* __restrict__ h16,
                      const unsigned* __restrict__ recs1,
                      const int* __restrict__ offs, const __half* __restrict__ comb16,
                      const int* __restrict__ perm,
                      __half* __restrict__ t16, int N) {
    int wid = (blockIdx.x * blockDim.x + threadIdx.x) >> 6;
    int lane = threadIdx.x & 63;
    if (wid >= N) return;
    int nid = perm[wid];  // wave-uniform
    int su = __builtin_amdgcn_readfirstlane(offs[nid]);
    int eu = __builtin_amdgcn_readfirstlane(offs[nid + 1]);
    h2v hm2 = ((const h2v*)h16)[nid * 64 + lane];  // scaled self row
    float hsx = (float)hm2[0], hsy = (float)hm2[1];
    if (su >= eu) {  // empty segment: m = 0; descale
        ((__half2*)t16)[nid * 64 + lane] =
            __floats2half2_rn(hsx * INV_L2E, hsy * INV_L2E);
        return;
    }
    float Sx = 0.f, Sy = 0.f, Wx = 0.f, Wy = 0.f;

    const h2v* hrow = (const h2v*)h16 + lane;    // row r at hrow[r*64]
    const h2v* crow = (const h2v*)comb16 + lane;
    const h2v zero2 = (h2v)(_Float16)0;

    h2v hq[16], cq[16];

    int e0 = su;
    do {
        int lastc = (eu < e0 + 64) ? eu : e0 + 64;  // chunk end (uniform)
        int last = lastc - 1;
        // one coalesced load covers this chunk's records
        int ridx = e0 + lane;
        ridx = (ridx < eu - 1) ? ridx : eu - 1;
        unsigned recv = recs1[ridx];

        auto load4 = [&](int base, int slot) {
#pragma unroll
            for (int i = 0; i < 4; ++i) {
                int idx = base + i; idx = (idx < last) ? idx : last;
                unsigned r = __builtin_amdgcn_readlane(recv, idx - e0);  // SGPR
                int sj = (int)(r & 0x1FFFFu);
                int cj = (int)(r >> 17);
                hq[slot * 4 + i] = hrow[sj * 64];   // saddr + lane*4
                cq[slot * 4 + i] = crow[cj * 64];
            }
        };
        // steady state: all 4 edges live -> no mask
        auto comp4u = [&](int slot) {
#pragma unroll
            for (int i = 0; i < 4; ++i) {
                h2v m = hq[slot * 4 + i] + cq[slot * 4 + i];   // v_pk_add_f16
                m = __builtin_elementwise_max(m, zero2);       // v_pk_max_f16
                float u0 = (float)m[0], u1 = (float)m[1];
                float px = __builtin_amdgcn_exp2f(u0);
                float py = __builtin_amdgcn_exp2f(u1);
                Sx += px; Sy += py;
                Wx = fmaf(px, u0, Wx);
                Wy = fmaf(py, u1, Wy);
            }
        };
        // tail: mask p (not u -- avoids 0*inf NaN in the W fma)
        auto comp4m = [&](int gb, int slot) {
#pragma unroll
            for (int i = 0; i < 4; ++i) {
                h2v m = hq[slot * 4 + i] + cq[slot * 4 + i];
                m = __builtin_elementwise_max(m, zero2);
                float u0 = (float)m[0], u1 = (float)m[1];
                bool valid = (gb + i) < eu;  // wave-uniform
                float px = valid ? __builtin_amdgcn_exp2f(u0) : 0.f;
                float py = valid ? __builtin_amdgcn_exp2f(u1) : 0.f;
                Sx += px; Sy += py;
                Wx = fmaf(px, u0, Wx);
                Wy = fmaf(py, u1, Wy);
            }
        };

        // prime: burst-issue up to 16 gathers (only live groups)
        load4(e0, 0);
        if (e0 + 4  < lastc) load4(e0 + 4, 1);
        if (e0 + 8  < lastc) load4(e0 + 8, 2);
        if (e0 + 12 < lastc) load4(e0 + 12, 3);

        int e = e0;
        for (; e + 16 < lastc; e += 16) {  // steady: all 16 current edges live
            comp4u(0); comp4u(1); comp4u(2); comp4u(3);
            load4(e + 16, 0); load4(e + 20, 1); load4(e + 24, 2); load4(e + 28, 3);
        }
        // tail: slots hold edges e..e+15 (clamped); masked compute
        comp4m(e, 0);
        if (e + 4  < lastc) comp4m(e + 4, 1);
        if (e + 8  < lastc) comp4m(e + 8, 2);
        if (e + 12 < lastc) comp4m(e + 12, 3);

        e0 = lastc;
    } while (e0 < eu);

    // t = (h_scaled + W/S) / L2E   (W,S in base-2 scaled domain)
    float tx = (hsx + Wx / (Sx + 1e-16f)) * INV_L2E;
    float ty = (hsy + Wy / (Sy + 1e-16f)) * INV_L2E;
    ((__half2*)t16)[nid * 64 + lane] = __floats2half2_rn(tx, ty);
}

// ------------------- Feature-split MFMA GEMM + fused LN(+ReLU) -------------
// Wave = 16 nodes x 64 feats (half row). Block = 4 waves = 32 nodes.
// wave: grp = wave>>1 (node group), half = wave&1 (feature half).
// D[f][node] = sum_k Wt16[f][k] * A16[node][k] via v_mfma_f32_16x16x32_f16;
// C/D: col(lane&15)=node, row(quad*4+reg)=f. LN: per-wave half-sums via
// shfl_xor(16,32), halves exchanged through 512B LDS (one barrier).
// MODE 0: hres16 = o (fp16); h16 = fp16(L2E*relu(LN(o))). MODE 1: out fp32.

template <int MODE>
__global__ __launch_bounds__(256) void k_gemm(const __half* __restrict__ A16,
                                              const __half* __restrict__ Wt16,
                                              const float* __restrict__ bl,
                                              const __half* __restrict__ res16,
                                              __half* __restrict__ hres16,
                                              const float* __restrict__ g,
                                              const float* __restrict__ bta,
                                              __half* __restrict__ h16,
                                              float* __restrict__ out,
                                              int N, int useRes) {
    __shared__ float2 sm[2][2][16];
    int lane = threadIdx.x & 63;
    int wave = threadIdx.x >> 6;
    int grp = wave >> 1, half = wave & 1;
    int quad = lane >> 4, col = lane & 15;
    int node = blockIdx.x * 32 + grp * 16 + col;
    bool nok = node < N;
    int nc = nok ? node : N - 1;  // clamp (row N-1 is valid data)

    const __half* arow = A16 + (size_t)nc * 128;
    half8 bfrag[4];
#pragma unroll
    for (int ks = 0; ks < 4; ++ks)
        bfrag[ks] = *(const half8*)(arow + ks * 32 + quad * 8);

    // prefetch residual half-row (overlaps with MFMA)
    uint2 rr[4];
    if (useRes) {
#pragma unroll
        for (int ft2 = 0; ft2 < 4; ++ft2) {
            int f0 = (half * 4 + ft2) * 16 + quad * 4;
            rr[ft2] = *(const uint2*)(res16 + (size_t)nc * 128 + f0);
        }
    }

    floatx4 acc[4];
#pragma unroll
    for (int ft2 = 0; ft2 < 4; ++ft2) acc[ft2] = (floatx4){0.f, 0.f, 0.f, 0.f};

#pragma unroll
    for (int ft2 = 0; ft2 < 4; ++ft2) {
        const __half* wrow = Wt16 + (size_t)((half * 4 + ft2) * 16 + col) * 128;
#pragma unroll
        for (int ks = 0; ks < 4; ++ks) {
            half8 afrag = *(const half8*)(wrow + ks * 32 + quad * 8);
            acc[ft2] = __builtin_amdgcn_mfma_f32_16x16x32_f16(afrag, bfrag[ks],
                                                              acc[ft2], 0, 0, 0);
        }
    }

    float s = 0.f, ss = 0.f;
#pragma unroll
    for (int ft2 = 0; ft2 < 4; ++ft2) {
        int f0 = (half * 4 + ft2) * 16 + quad * 4;
        float4 bb = *(const float4*)(bl + f0);
        float o0 = acc[ft2][0] + bb.x, o1 = acc[ft2][1] + bb.y;
        float o2 = acc[ft2][2] + bb.z, o3 = acc[ft2][3] + bb.w;
        if (useRes) {
            __half2 r01 = *(__half2*)&rr[ft2].x, r23 = *(__half2*)&rr[ft2].y;
            o0 += __low2float(r01); o1 += __high2float(r01);
            o2 += __low2float(r23); o3 += __high2float(r23);
        }
        acc[ft2][0] = o0; acc[ft2][1] = o1; acc[ft2][2] = o2; acc[ft2][3] = o3;
        s += (o0 + o1) + (o2 + o3);
        ss += fmaf(o0, o0, o1 * o1) + fmaf(o2, o2, o3 * o3);
        if (MODE == 0 && nok) {
            __half2 h01 = __floats2half2_rn(o0, o1);
            __half2 h23 = __floats2half2_rn(o2, o3);
            uint2 pk = make_uint2(*(unsigned*)&h01, *(unsigned*)&h23);
            *(uint2*)(hres16 + (size_t)node * 128 + f0) = pk;
        }
    }
    // reduce over quads -> half-row sums (all lanes hold their col's sum)
    s += __shfl_xor(s, 16, 64);  ss += __shfl_xor(ss, 16, 64);
    s += __shfl_xor(s, 32, 64);  ss += __shfl_xor(ss, 32, 64);
    if (quad == 0) sm[grp][half][col] = make_float2(s, ss);
    __syncthreads();
    float2 oth = sm[grp][half ^ 1][col];
    float st = s + oth.x, sst = ss + oth.y;
    float mu = st * (1.f / 128.f);
    float var = sst * (1.f / 128.f) - mu * mu;
    float rs = rsqrtf(var + 1e-5f);

#pragma unroll
    for (int ft2 = 0; ft2 < 4; ++ft2) {
        int f0 = (half * 4 + ft2) * 16 + quad * 4;
        float4 gg = *(const float4*)(g + f0);
        float4 bt = *(const float4*)(bta + f0);
        float l0 = (acc[ft2][0] - mu) * rs * gg.x + bt.x;
        float l1 = (acc[ft2][1] - mu) * rs * gg.y + bt.y;
        float l2 = (acc[ft2][2] - mu) * rs * gg.z + bt.z;
        float l3 = (acc[ft2][3] - mu) * rs * gg.w + bt.w;
        if (MODE == 0) {
            l0 = fmaxf(l0, 0.f); l1 = fmaxf(l1, 0.f);
            l2 = fmaxf(l2, 0.f); l3 = fmaxf(l3, 0.f);
            if (nok) {
                __half2 h01 = __floats2half2_rn(l0 * L2E, l1 * L2E);
                __half2 h23 = __floats2half2_rn(l2 * L2E, l3 * L2E);
                uint2 pk = make_uint2(*(unsigned*)&h01, *(unsigned*)&h23);
                *(uint2*)(h16 + (size_t)node * 128 + f0) = pk;
            }
        } else {
            if (nok)
                *(float4*)(out + (size_t)node * 128 + f0) =
                    make_float4(l0, l1, l2, l3);
        }
    }
}

// ------------------------- Launch -------------------------

extern "C" void kernel_launch(void* const* d_in, const int* in_sizes, int n_in,
                              void* d_out, int out_size, void* d_ws, size_t ws_size,
                              hipStream_t stream) {
    const int*   x    = (const int*)d_in[0];
    const int*   ei   = (const int*)d_in[1];
    const int*   attr = (const int*)d_in[2];
    const float* aemb = (const float*)d_in[3];
    const float* bemb = (const float*)d_in[4];
    const float* Wf   = (const float*)d_in[5];
    const float* bf   = (const float*)d_in[6];
    const float* gam  = (const float*)d_in[7];
    const float* bet  = (const float*)d_in[8];
    float* out = (float*)d_out;

    const int N = in_sizes[0] / NA;        // 50000
    const int E = in_sizes[1] / 2;         // 625000
    const int L = in_sizes[5] / (D * D);   // 7

    char* ws = (char*)d_ws;
    size_t o = 0;
    auto carve = [&](size_t bytes) -> void* {
        void* p = (void*)(ws + o);
        o += (bytes + 255) & ~(size_t)255;
        return p;
    };
    __half* hres16 = (__half*)carve((size_t)N * D * 2);  // fp16 residual chain
    __half* h16    = (__half*)carve((size_t)N * D * 2);  // fp16 gather table (x L2E)
    __half* t16    = (__half*)carve((size_t)N * D * 2);  // fp16 agg output
    unsigned* recs1 = (unsigned*)carve((size_t)E * 4);   // packed records
    __half* comb16 = (__half*)carve(512 * D * 2);
    __half* Wt16   = (__half*)carve((size_t)L * D * D * 2);
    int*    deg    = (int*)carve((size_t)N * 4);
    int*    cur    = (int*)carve((size_t)N * 4);
    int*    offs   = (int*)carve((size_t)(N + 1) * 4);
    int*    perm   = (int*)carve((size_t)N * 4);
    int*    dbin   = (int*)carve(256);
    int*    doff   = (int*)carve(256);
    int*    dcur   = (int*)carve(256);
    int*    bsum   = (int*)carve(4096);
    int*    bexc   = (int*)carve(4096);

    const int* src = ei;
    const int* dst = ei + E;

    int ebl = (E + 255) / 256;
    int nbl = (N + 255) / 256;  // 196 (<=256 required by k_scan_b)

    // k_comb also zeroes deg/cur/dbin/dcur -> grid must cover N threads
    k_comb<<<nbl, 256, 0, stream>>>(bemb, comb16, deg, cur, dbin, dcur, N);
    int wtot = L * D * D;
    k_wt<<<(wtot + 255) / 256, 256, 0, stream>>>(Wf, Wt16, wtot);
    k_hist<<<ebl, 256, 0, stream>>>(dst, deg, E);
    k_scan_a<<<nbl, 256, 0, stream>>>(deg, offs, bsum, N);
    k_scan_b<<<1, 256, 0, stream>>>(bsum, bexc, nbl);
    k_scan_c_dhist<<<nbl, 256, 0, stream>>>(offs, bexc, deg, dbin, N);
    k_fill<<<ebl, 256, 0, stream>>>(src, dst, attr, offs, cur, recs1, dbin, doff, E);
    k_dfill<<<nbl, 256, 0, stream>>>(deg, doff, dcur, perm, N);

    int wbl = (N * 64 + 255) / 256;  // wave per node
    k_atom<<<wbl, 256, 0, stream>>>(x, aemb, h16, N);

    int gbl = (N + 31) / 32;  // 1563 blocks, 32 nodes each (feature-split)
    for (int l = 0; l < L; ++l) {
        k_agg<<<wbl, 256, 0, stream>>>(h16, recs1, offs, comb16, perm, t16, N);
        if (l == L - 1) {
            k_gemm<1><<<gbl, 256, 0, stream>>>(t16, Wt16 + l * D * D, bf + l * D,
                                               hres16, hres16,
                                               gam + l * D, bet + l * D, h16, out,
                                               N, 1);
        } else {
            k_gemm<0><<<gbl, 256, 0, stream>>>(t16, Wt16 + l * D * D, bf + l * D,
                                               hres16, hres16,
                                               gam + l * D, bet + l * D, h16, out,
                                               N, l > 0 ? 1 : 0);
        }
    }
}